// Round 1
// baseline (100.522 us; speedup 1.0000x reference)
//
#include <hip/hip_runtime.h>

// Problem constants (match reference)
#define C_DIM 16
#define R_DIM 1024
#define T_DIM 4096
#define N_PTS 500000

// ws layout: [0, C*T*4) : int32 maxrho[C][T]
// out: float out[C][R][T]  (C*R*T = 67,108,864 floats = 256 MB)

__global__ void init_maxrho(int* __restrict__ maxrho) {
    int i = blockIdx.x * blockDim.x + threadIdx.x;
    if (i < C_DIM * T_DIM) maxrho[i] = -1;
}

__global__ void scatter_max(const int* __restrict__ rho,
                            const int* __restrict__ theta,
                            const int* __restrict__ f,
                            int* __restrict__ maxrho, int n) {
    int i = blockIdx.x * blockDim.x + threadIdx.x;
    if (i < n) {
        int c = f[i];
        int t = theta[i];
        atomicMax(&maxrho[c * T_DIM + t], rho[i]);
    }
}

// One float4 (4 consecutive t) per thread.
// i4 in [0, C*R*T/4). t4 = i4 % (T/4); row = i4 / (T/4); rr = row % R; c = row / R.
__global__ void write_out(const int* __restrict__ maxrho,
                          const float* __restrict__ rp,
                          const float* __restrict__ r,
                          float* __restrict__ out) {
    int i4 = blockIdx.x * blockDim.x + threadIdx.x;   // < 16,777,216
    int t4  = i4 & (T_DIM / 4 - 1);                   // 0..1023
    int row = i4 >> 10;                               // c*R + rr, 0..16383
    int rr  = row & (R_DIM - 1);
    int c   = row >> 10;

    const int4 m = reinterpret_cast<const int4*>(maxrho + c * T_DIM)[t4];
    float rv = r[rr];

    float4 o;
    o.x = rp[m.x < 0 ? R_DIM : m.x] - rv;
    o.y = rp[m.y < 0 ? R_DIM : m.y] - rv;
    o.z = rp[m.z < 0 ? R_DIM : m.z] - rv;
    o.w = rp[m.w < 0 ? R_DIM : m.w] - rv;

    reinterpret_cast<float4*>(out)[i4] = o;
}

extern "C" void kernel_launch(void* const* d_in, const int* in_sizes, int n_in,
                              void* d_out, int out_size, void* d_ws, size_t ws_size,
                              hipStream_t stream) {
    const int*   rho   = (const int*)d_in[0];
    const int*   theta = (const int*)d_in[1];
    const int*   f     = (const int*)d_in[2];
    const float* rp    = (const float*)d_in[3];
    const float* r     = (const float*)d_in[4];
    float* out = (float*)d_out;

    int* maxrho = (int*)d_ws;   // C*T*4 = 256 KB

    const int n = in_sizes[0];

    // 1. init maxrho = -1 (must re-run every call; harness doesn't re-poison)
    {
        int total = C_DIM * T_DIM;
        init_maxrho<<<(total + 255) / 256, 256, 0, stream>>>(maxrho);
    }
    // 2. scatter atomicMax
    scatter_max<<<(n + 255) / 256, 256, 0, stream>>>(rho, theta, f, maxrho, n);
    // 3. broadcast write, float4 per thread
    {
        int total4 = (C_DIM * R_DIM * T_DIM) / 4;     // 16,777,216
        write_out<<<total4 / 256, 256, 0, stream>>>(maxrho, rp, r, out);
    }
}

// Round 2
// 73.264 us; speedup vs baseline: 1.3721x; 1.3721x over previous
//
#include <hip/hip_runtime.h>

// Problem constants (match reference)
#define C_DIM 16
#define R_DIM 1024
#define T_DIM 4096

// ws layout: [0, C*T*4) = 256 KB, used first as int32 maxrho[C][T],
// then resolved IN-PLACE to float val[C][T] = rp[maxrho<0 ? R : maxrho].
// out: float out[C][R][T] = 256 MB.

__global__ void scatter_max(const int* __restrict__ rho,
                            const int* __restrict__ theta,
                            const int* __restrict__ f,
                            int* __restrict__ maxrho, int n) {
    int i = blockIdx.x * blockDim.x + threadIdx.x;
    if (i < n) {
        atomicMax(&maxrho[f[i] * T_DIM + theta[i]], rho[i]);
    }
}

// maxrho (int) -> val (float) in-place: val = rp[m < 0 ? R : m]
__global__ void resolve(int* __restrict__ slot,
                        const float* __restrict__ rp) {
    int i = blockIdx.x * blockDim.x + threadIdx.x;   // < C*T = 65536
    int m = slot[i];
    float v = rp[m < 0 ? R_DIM : m];
    reinterpret_cast<float*>(slot)[i] = v;
}

// One block per (c, rr) output row: 256 threads x 4 float4 = 4096 floats.
// rr/c derive from blockIdx only -> r[rr] is a scalar (wave-uniform) load.
__global__ void write_out(const float* __restrict__ val,
                          const float* __restrict__ r,
                          float* __restrict__ out) {
    int row = blockIdx.x;                 // c*R + rr, 0..16383
    int rr  = row & (R_DIM - 1);
    int c   = row >> 10;
    float rv = r[rr];

    const float4* vrow = reinterpret_cast<const float4*>(val + c * T_DIM);
    float4* orow = reinterpret_cast<float4*>(out) + (size_t)row * (T_DIM / 4);

#pragma unroll
    for (int k = 0; k < 4; ++k) {
        int t4 = threadIdx.x + k * 256;
        float4 v = vrow[t4];
        float4 o = { v.x - rv, v.y - rv, v.z - rv, v.w - rv };
        orow[t4] = o;
    }
}

extern "C" void kernel_launch(void* const* d_in, const int* in_sizes, int n_in,
                              void* d_out, int out_size, void* d_ws, size_t ws_size,
                              hipStream_t stream) {
    const int*   rho   = (const int*)d_in[0];
    const int*   theta = (const int*)d_in[1];
    const int*   f     = (const int*)d_in[2];
    const float* rp    = (const float*)d_in[3];
    const float* r     = (const float*)d_in[4];
    float* out = (float*)d_out;

    int* slot = (int*)d_ws;                 // C*T*4 = 256 KB
    const int n = in_sizes[0];

    // 1. maxrho = -1 via byte-memset 0xFF (graph-capture-safe async memset)
    hipMemsetAsync(slot, 0xFF, (size_t)C_DIM * T_DIM * sizeof(int), stream);

    // 2. scatter atomicMax into maxrho
    scatter_max<<<(n + 255) / 256, 256, 0, stream>>>(rho, theta, f, slot, n);

    // 3. resolve maxrho -> rp-value, in place (65536 elems)
    resolve<<<(C_DIM * T_DIM) / 256, 256, 0, stream>>>(slot, rp);

    // 4. stream the 256 MB output: val row minus uniform r[rr]
    write_out<<<C_DIM * R_DIM, 256, 0, stream>>>((const float*)slot, r, out);
}